// Round 9
// baseline (5043.158 us; speedup 1.0000x reference)
//
#include <hip/hip_runtime.h>
#include <hip/hip_fp16.h>
#include <math.h>

#define TT 512
#define BB 16
#define EE 100
#define HD 500
#define NEG (-10000.0f)

typedef __attribute__((ext_vector_type(8))) short short8;
typedef __attribute__((ext_vector_type(4))) float f32x4;

__device__ inline short f2bf(float f) {
    unsigned u = __builtin_bit_cast(unsigned, f);
    unsigned r = (u + 0x7fffu + ((u >> 16) & 1u)) >> 16;
    return (short)r;
}
__device__ inline unsigned short f2h(float f) {
    __half h = __float2half(f);
    return __builtin_bit_cast(unsigned short, h);
}
__device__ inline float h2f(unsigned short u) {
    __half h = __builtin_bit_cast(__half, u);
    return __half2float(h);
}

// ---------------- embedding gather -> bf16 XS (T*B, 128) zero-padded ----------------
__global__ void embed_kernel(const int* __restrict__ x, const float* __restrict__ EW,
                             unsigned short* __restrict__ XS) {
    int idx = blockIdx.x * 256 + threadIdx.x;    // < 8192*128
    int e = idx & 127;
    int r = idx >> 7;          // r = t*16 + b
    int t = r >> 4;
    int b = r & 15;
    unsigned short v = 0;
    if (e < EE) {
        int tok = x[b * TT + t];
        v = (unsigned short)f2bf(EW[(size_t)tok * EE + e]);
    }
    XS[idx] = v;
}

// ---------------- fp32 -> bf16 weight conversion with K padding ----------------
__global__ void wconv_kernel(const float* __restrict__ src, unsigned short* __restrict__ dst,
                             int Ksrc, int Kpad, int total) {
    int i = blockIdx.x * 256 + threadIdx.x;
    if (i >= total) return;
    int r = i / Kpad;
    int k = i - r * Kpad;
    dst[i] = (k < Ksrc) ? (unsigned short)f2bf(src[(size_t)r * Ksrc + k]) : 0;
}

// ---------------- zero scratch (hglob + barriers) ----------------
__global__ void zero_kernel(int* __restrict__ p, int n) {
    int i = blockIdx.x * 256 + threadIdx.x;
    if (i < n) p[i] = 0;
}

// ---------------- zero the pad columns (1000..1023) of bf16 H0 ----------------
__global__ void padzero_kernel(int* __restrict__ p) {
    int i = blockIdx.x * 256 + threadIdx.x;      // < 8192*12
    if (i >= 8192 * 12) return;
    int r = i / 12, c = i - r * 12;
    p[r * 512 + 500 + c] = 0;                    // shorts 1000..1023 = ints 500..511
}

// ------------- bf16 MFMA GEMM: C[z] = f16(A @ W[z]^T + b1[z] + b2[z]) --------------
// A: (8192, Kpad) bf16. W: (2, 2000, Kpad) bf16. C: (2, 8192, 2000) fp16.
__global__ __launch_bounds__(256) void gemm_mfma(
    const unsigned short* __restrict__ A, const unsigned short* __restrict__ W,
    const float* __restrict__ b1, const float* __restrict__ b2,
    unsigned short* __restrict__ C, int Kpad) {
    __shared__ __align__(16) unsigned short AsS[128 * 40];
    __shared__ __align__(16) unsigned short WsS[64 * 40];
    const int tid = threadIdx.x;
    const int lane = tid & 63;
    const int w = tid >> 6;
    const int quad = lane >> 4;
    const int nl = lane & 15;
    const int bm0 = blockIdx.x * 128;
    const int n0 = blockIdx.y * 64;
    const int z = blockIdx.z;

    const unsigned short* Wz = W + (size_t)z * 2000 * Kpad;
    unsigned short* Cz = C + (size_t)z * 8192 * 2000;
    const float* b1z = b1 + (size_t)z * 2000;
    const float* b2z = b2 + (size_t)z * 2000;

    f32x4 acc[2][4];
#pragma unroll
    for (int mt = 0; mt < 2; ++mt)
#pragma unroll
        for (int nt = 0; nt < 4; ++nt) acc[mt][nt] = (f32x4){0.f, 0.f, 0.f, 0.f};

    const int arow = tid >> 2;
    const int kc = tid & 3;
    const int wn = n0 + arow;

    for (int k0 = 0; k0 < Kpad; k0 += 32) {
        short8 av0 = *(const short8*)(A + (size_t)(bm0 + arow) * Kpad + k0 + kc * 8);
        short8 av1 = *(const short8*)(A + (size_t)(bm0 + 64 + arow) * Kpad + k0 + kc * 8);
        short8 wv = {0, 0, 0, 0, 0, 0, 0, 0};
        if (wn < 2000) wv = *(const short8*)(Wz + (size_t)wn * Kpad + k0 + kc * 8);
        __syncthreads();
        *(short8*)&AsS[arow * 40 + kc * 8] = av0;
        *(short8*)&AsS[(64 + arow) * 40 + kc * 8] = av1;
        *(short8*)&WsS[arow * 40 + kc * 8] = wv;
        __syncthreads();

        short8 af[2], bfr[4];
#pragma unroll
        for (int mt = 0; mt < 2; ++mt)
            af[mt] = *(const short8*)&AsS[(w * 32 + mt * 16 + nl) * 40 + quad * 8];
#pragma unroll
        for (int nt = 0; nt < 4; ++nt)
            bfr[nt] = *(const short8*)&WsS[(nt * 16 + nl) * 40 + quad * 8];
#pragma unroll
        for (int mt = 0; mt < 2; ++mt)
#pragma unroll
            for (int nt = 0; nt < 4; ++nt)
                acc[mt][nt] = __builtin_amdgcn_mfma_f32_16x16x32_bf16(
                    af[mt], bfr[nt], acc[mt][nt], 0, 0, 0);
    }

#pragma unroll
    for (int nt = 0; nt < 4; ++nt) {
        int n = n0 + nt * 16 + nl;
        if (n < 2000) {
            float bb = b1z[n] + b2z[n];
#pragma unroll
            for (int mt = 0; mt < 2; ++mt) {
                int mbase = bm0 + w * 32 + mt * 16 + quad * 4;
#pragma unroll
                for (int reg = 0; reg < 4; ++reg)
                    Cz[(size_t)(mbase + reg) * 2000 + n] = f2h(acc[mt][nt][reg] + bb);
            }
        }
    }
}

// ---------------- persistent-weight recurrence, bf16 MFMA, L3-atomic sync ----------
// R8-proven skeleton. R9 deltas: (1) poll with 16 threads/block (1 counter each)
// + trailing __syncthreads (16x less MALL poll traffic); (2) Hout stores deferred
// until after the counter add so the pre-add vmcnt(0) drain only waits the 4
// h-publish atomic stores.
#define NBLK_DIR 16
#define CNT_STRIDE 64

union U16 { unsigned long long u[2]; short8 s; };

__global__ __launch_bounds__(256, 1) void rec8_kernel(
    const unsigned short* __restrict__ G, const float* __restrict__ Whh,
    const int* __restrict__ x, const float* __restrict__ h0,
    const float* __restrict__ c0, int layerbase,
    void* __restrict__ Houtv, int hbf16,
    unsigned short* __restrict__ hglob, int* __restrict__ bar)
{
    const int blk = blockIdx.x;
    const int dir = blk >> 4;
    const int bsl = blk & 15;
    const int k0 = bsl * 32;
    const int tid = threadIdx.x;
    const int lane = tid & 63;
    const int w = tid >> 6;          // wave 0..3
    const int quad = lane >> 4;      // 0..3
    const int nl = lane & 15;

    const float* Wd = Whh + (size_t)dir * 2000 * HD;
    const unsigned short* Gd = G + (size_t)dir * TT * BB * 2000;
    unsigned short* hgA = hglob + (dir * 2 + 0) * 8192;
    unsigned short* hgB = hglob + (dir * 2 + 1) * 8192;
    int* cntB  = bar + (dir * NBLK_DIR) * CNT_STRIDE;
    int* mycnt = cntB + bsl * CNT_STRIDE;
    const int* pollAddr = cntB + (tid & 15) * CNT_STRIDE;   // tid<16 pollers

    __shared__ float sg[4][32][17];

    // ---- load weights into registers as B fragments (bf16) ----
    short8 bf[2][16];
#pragma unroll
    for (int tl = 0; tl < 2; ++tl) {
        int tt = w * 2 + tl;
        int r = tt * 16 + nl;          // 0..127 local gate row
        int g = r >> 5;                // gate 0..3
        int lkr = r & 31;
        int kk = k0 + lkr;             // output h index
        const float* wrow = (kk < HD) ? (Wd + (size_t)(g * HD + kk) * HD) : (const float*)0;
#pragma unroll
        for (int ks = 0; ks < 16; ++ks) {
            int kg0 = ks * 32 + quad * 8;
            short8 v;
            if (wrow && kg0 + 8 <= HD) {
                float4 f0 = *(const float4*)(wrow + kg0);
                float4 f1 = *(const float4*)(wrow + kg0 + 4);
                v[0] = f2bf(f0.x); v[1] = f2bf(f0.y); v[2] = f2bf(f0.z); v[3] = f2bf(f0.w);
                v[4] = f2bf(f1.x); v[5] = f2bf(f1.y); v[6] = f2bf(f1.z); v[7] = f2bf(f1.w);
            } else {
#pragma unroll
                for (int j = 0; j < 8; ++j) {
                    int kg = kg0 + j;
                    float f = (wrow && kg < HD) ? wrow[kg] : 0.f;
                    v[j] = f2bf(f);
                }
            }
            bf[tl][ks] = v;
        }
    }

    // ---- per-thread persistent state: 2 (b,k) pairs, same k different b ----
    const int lk = tid & 31;
    const int k  = k0 + lk;
    const bool kok = (k < HD);
    const int b0v = tid >> 5;          // 0..7
    const int b1v = 8 + (tid >> 5);    // 8..15
    float h_st[2] = {0.f, 0.f}, c_st[2] = {0.f, 0.f};
    if (kok) {
        size_t base0 = (size_t)(layerbase + dir) * BB * HD + (size_t)b0v * HD + k;
        size_t base1 = (size_t)(layerbase + dir) * BB * HD + (size_t)b1v * HD + k;
        h_st[0] = h0[base0]; c_st[0] = c0[base0];
        h_st[1] = h0[base1]; c_st[1] = c0[base1];
    }

    // ---- publish h0 into hgA (packed 8B atomic stores; k>=HD slots stay zeroed) ----
    {
        int i0 = (int)(unsigned short)f2bf(kok ? h_st[0] : 0.f);
        int i1 = (int)(unsigned short)f2bf(kok ? h_st[1] : 0.f);
        int a0 = __shfl_down(i0, 1), c0s = __shfl_down(i0, 2), d0 = __shfl_down(i0, 3);
        int a1 = __shfl_down(i1, 1), c1s = __shfl_down(i1, 2), d1 = __shfl_down(i1, 3);
        if ((lk & 3) == 0 && kok) {
            unsigned long long p0 = (unsigned long long)(unsigned)(i0 | (a0 << 16))
                                  | ((unsigned long long)(unsigned)(c0s | (d0 << 16)) << 32);
            unsigned long long p1 = (unsigned long long)(unsigned)(i1 | (a1 << 16))
                                  | ((unsigned long long)(unsigned)(c1s | (d1 << 16)) << 32);
            int idx0 = bsl * 512 + (b0v + 16 * (lk >> 3)) * 8 + (lk & 7);
            int idx1 = bsl * 512 + (b1v + 16 * (lk >> 3)) * 8 + (lk & 7);
            __hip_atomic_store((unsigned long long*)(hgA + idx0), p0,
                               __ATOMIC_RELAXED, __HIP_MEMORY_SCOPE_AGENT);
            __hip_atomic_store((unsigned long long*)(hgA + idx1), p1,
                               __ATOMIC_RELAXED, __HIP_MEMORY_SCOPE_AGENT);
        }
    }

    // ---- init barrier (16 pollers) ----
    __threadfence_block();
    __syncthreads();
    if (tid == 0)
        __hip_atomic_fetch_add(mycnt, 1, __ATOMIC_RELAXED, __HIP_MEMORY_SCOPE_AGENT);
    if (tid < 16)
        while (__hip_atomic_load(pollAddr, __ATOMIC_RELAXED, __HIP_MEMORY_SCOPE_AGENT) < 1) { }
    __syncthreads();

    // ---- prefetch step-0 G (raw) + mask ----
    unsigned short gpraw[2][4]; int m[2];
    m[0] = m[1] = 0;
    gpraw[0][0]=gpraw[0][1]=gpraw[0][2]=gpraw[0][3]=0;
    gpraw[1][0]=gpraw[1][1]=gpraw[1][2]=gpraw[1][3]=0;
    {
        int t = dir ? (TT - 1) : 0;
        if (kok) {
            const unsigned short* gr0 = Gd + ((size_t)t * BB + b0v) * 2000 + k;
            const unsigned short* gr1 = Gd + ((size_t)t * BB + b1v) * 2000 + k;
            gpraw[0][0] = gr0[0]; gpraw[0][1] = gr0[HD]; gpraw[0][2] = gr0[2 * HD]; gpraw[0][3] = gr0[3 * HD];
            gpraw[1][0] = gr1[0]; gpraw[1][1] = gr1[HD]; gpraw[1][2] = gr1[2 * HD]; gpraw[1][3] = gr1[3 * HD];
            m[0] = x[b0v * TT + t] > 0;
            m[1] = x[b1v * TT + t] > 0;
        }
    }

    for (int s = 0; s < TT; ++s) {
        const int t = dir ? (TT - 1 - s) : s;
        const unsigned short* hr = (s & 1) ? hgB : hgA;
        unsigned short* hw = (s & 1) ? hgA : hgB;

        // ---- issue ALL 32 h-fragment atomic loads first (pipelined, one latency) ----
        const unsigned long long* h64 = (const unsigned long long*)hr;
        unsigned long long v[32];
#pragma unroll
        for (int ks = 0; ks < 16; ++ks) {
            v[2 * ks]     = __hip_atomic_load(h64 + ks * 128 + lane * 2,
                                              __ATOMIC_RELAXED, __HIP_MEMORY_SCOPE_AGENT);
            v[2 * ks + 1] = __hip_atomic_load(h64 + ks * 128 + lane * 2 + 1,
                                              __ATOMIC_RELAXED, __HIP_MEMORY_SCOPE_AGENT);
        }

        // ---- recurrent preactivation via MFMA ----
        f32x4 acc0 = {0.f, 0.f, 0.f, 0.f};
        f32x4 acc1 = {0.f, 0.f, 0.f, 0.f};
#pragma unroll
        for (int ks = 0; ks < 16; ++ks) {
            U16 u;
            u.u[0] = v[2 * ks];
            u.u[1] = v[2 * ks + 1];
            acc0 = __builtin_amdgcn_mfma_f32_16x16x32_bf16(u.s, bf[0][ks], acc0, 0, 0, 0);
            acc1 = __builtin_amdgcn_mfma_f32_16x16x32_bf16(u.s, bf[1][ks], acc1, 0, 0, 0);
        }

        // ---- scatter D to LDS: sg[gate][lk][b] ----
        {
            int r0 = (w * 2 + 0) * 16 + nl;
            int r1 = (w * 2 + 1) * 16 + nl;
            int g0r = r0 >> 5, lk0 = r0 & 31;
            int g1r = r1 >> 5, lk1 = r1 & 31;
#pragma unroll
            for (int reg = 0; reg < 4; ++reg) {
                int b = quad * 4 + reg;
                sg[g0r][lk0][b] = acc0[reg];
                sg[g1r][lk1][b] = acc1[reg];
            }
        }
        __syncthreads();

        // ---- epilogue: gates, state update (Hout deferred) ----
        float houtv[2] = {0.f, 0.f};
        if (kok) {
#pragma unroll
            for (int p = 0; p < 2; ++p) {
                int b = p ? b1v : b0v;
                float si  = sg[0][lk][b] + h2f(gpraw[p][0]);
                float sf  = sg[1][lk][b] + h2f(gpraw[p][1]);
                float sgg = sg[2][lk][b] + h2f(gpraw[p][2]);
                float so  = sg[3][lk][b] + h2f(gpraw[p][3]);
                float ig = 1.f / (1.f + __expf(-si));
                float fg = 1.f / (1.f + __expf(-sf));
                float gg = tanhf(sgg);
                float og = 1.f / (1.f + __expf(-so));
                float c_new = fg * c_st[p] + ig * gg;
                float h_new = og * tanhf(c_new);
                float hn = m[p] ? h_new : h_st[p];
                float cn = m[p] ? c_new : c_st[p];
                h_st[p] = hn; c_st[p] = cn;
                houtv[p] = m[p] ? h_new : 0.f;
            }
        }

        // ---- publish h into hw (packed 8B atomic stores) ----
        {
            int i0 = (int)(unsigned short)f2bf(kok ? h_st[0] : 0.f);
            int i1 = (int)(unsigned short)f2bf(kok ? h_st[1] : 0.f);
            int a0 = __shfl_down(i0, 1), c0s = __shfl_down(i0, 2), d0 = __shfl_down(i0, 3);
            int a1 = __shfl_down(i1, 1), c1s = __shfl_down(i1, 2), d1 = __shfl_down(i1, 3);
            if ((lk & 3) == 0 && kok) {
                unsigned long long p0 = (unsigned long long)(unsigned)(i0 | (a0 << 16))
                                      | ((unsigned long long)(unsigned)(c0s | (d0 << 16)) << 32);
                unsigned long long p1 = (unsigned long long)(unsigned)(i1 | (a1 << 16))
                                      | ((unsigned long long)(unsigned)(c1s | (d1 << 16)) << 32);
                int idx0 = bsl * 512 + (b0v + 16 * (lk >> 3)) * 8 + (lk & 7);
                int idx1 = bsl * 512 + (b1v + 16 * (lk >> 3)) * 8 + (lk & 7);
                __hip_atomic_store((unsigned long long*)(hw + idx0), p0,
                                   __ATOMIC_RELAXED, __HIP_MEMORY_SCOPE_AGENT);
                __hip_atomic_store((unsigned long long*)(hw + idx1), p1,
                                   __ATOMIC_RELAXED, __HIP_MEMORY_SCOPE_AGENT);
            }
        }

        if (s + 1 < TT) {
            // ---- drain h stores only, bump counter ----
            __threadfence_block();
            __syncthreads();
            if (tid == 0)
                __hip_atomic_fetch_add(mycnt, 1, __ATOMIC_RELAXED, __HIP_MEMORY_SCOPE_AGENT);

            // ---- Hout stores for this step (overlap the poll; needed only by
            //      the next kernel, flushed at kernel end) ----
            if (kok) {
#pragma unroll
                for (int p = 0; p < 2; ++p) {
                    int b = p ? b1v : b0v;
                    if (hbf16)
                        ((unsigned short*)Houtv)[((size_t)t * BB + b) * 1024 + dir * HD + k] =
                            (unsigned short)f2bf(houtv[p]);
                    else
                        ((float*)Houtv)[((size_t)t * BB + b) * 1000 + dir * HD + k] = houtv[p];
                }
            }

            // ---- prefetch next step's G (raw) + mask: overlaps the poll below ----
            int tn = dir ? (TT - 2 - s) : (s + 1);
            if (kok) {
                const unsigned short* gr0 = Gd + ((size_t)tn * BB + b0v) * 2000 + k;
                const unsigned short* gr1 = Gd + ((size_t)tn * BB + b1v) * 2000 + k;
                gpraw[0][0] = gr0[0]; gpraw[0][1] = gr0[HD]; gpraw[0][2] = gr0[2 * HD]; gpraw[0][3] = gr0[3 * HD];
                gpraw[1][0] = gr1[0]; gpraw[1][1] = gr1[HD]; gpraw[1][2] = gr1[2 * HD]; gpraw[1][3] = gr1[3 * HD];
                m[0] = x[b0v * TT + tn] > 0;
                m[1] = x[b1v * TT + tn] > 0;
            }

            // ---- poll: 16 threads, one counter each; syncthreads releases block ----
            if (tid < 16)
                while (__hip_atomic_load(pollAddr, __ATOMIC_RELAXED,
                                         __HIP_MEMORY_SCOPE_AGENT) < s + 2) { }
            __syncthreads();
        } else {
            // last step: just write Hout (flushed at kernel end)
            if (kok) {
#pragma unroll
                for (int p = 0; p < 2; ++p) {
                    int b = p ? b1v : b0v;
                    if (hbf16)
                        ((unsigned short*)Houtv)[((size_t)t * BB + b) * 1024 + dir * HD + k] =
                            (unsigned short)f2bf(houtv[p]);
                    else
                        ((float*)Houtv)[((size_t)t * BB + b) * 1000 + dir * HD + k] = houtv[p];
                }
            }
        }
    }
}

// ---------------- output projection: Y (T,B,32) = HS @ Wo^T + bo, masked ------------
__global__ void outproj_kernel(const float* __restrict__ HS, const float* __restrict__ Wo,
                               const float* __restrict__ bo, const int* __restrict__ x,
                               float* __restrict__ Y) {
    int idx = blockIdx.x * 256 + threadIdx.x;
    int r = idx >> 5;
    int n = idx & 31;
    int t = r >> 4;
    int b = r & 15;
    float out = 0.f;
    if (x[b * TT + t] > 0) {
        const float4* h4 = (const float4*)(HS + (size_t)r * 1000);
        const float4* w4 = (const float4*)(Wo + (size_t)n * 1000);
        float s = 0.f;
#pragma unroll 4
        for (int q = 0; q < 250; ++q) {
            float4 a = h4[q]; float4 w = w4[q];
            s += a.x * w.x + a.y * w.y + a.z * w.z + a.w * w.w;
        }
        out = s + bo[n];
    }
    Y[idx] = out;
}

// ---------------- CRF: gold score + forward scan ----------------
__global__ __launch_bounds__(1024) void crf_kernel(
    const float* __restrict__ Y, const int* __restrict__ x, const int* __restrict__ y0,
    const float* __restrict__ trans, float* __restrict__ out_pb) {
    int b = blockIdx.x;
    int tid = threadIdx.x;
    int i = tid >> 5;
    int j = tid & 31;
    float tr_ij = trans[i * 32 + j];

    __shared__ float sc[32];
    __shared__ float wred[16];
    __shared__ float goldS;

    float gp = 0.f;
    if (tid < TT) {
        int t = tid;
        int xm = x[b * TT + t];
        float mf = (xm > 0) ? 1.f : 0.f;
        int ynext = y0[b * TT + t];
        int yprev = (t == 0) ? 1 : y0[b * TT + t - 1];
        gp = Y[((size_t)t * BB + b) * 32 + ynext] + trans[ynext * 32 + yprev] * mf;
    }
#pragma unroll
    for (int d = 32; d >= 1; d >>= 1) gp += __shfl_down(gp, d);
    if ((tid & 63) == 0) wred[tid >> 6] = gp;
    __syncthreads();
    if (tid == 0) {
        float s = 0.f;
        for (int ww = 0; ww < 16; ++ww) s += wred[ww];
        goldS = s;
    }
    if (tid < 32) sc[tid] = (tid == 1) ? 0.f : NEG;
    __syncthreads();

    for (int t = 0; t < TT; ++t) {
        float sj = sc[j];
        float z = sj + tr_ij;
        float mx = z;
#pragma unroll
        for (int d = 16; d >= 1; d >>= 1) mx = fmaxf(mx, __shfl_xor(mx, d));
        float e = __expf(z - mx);
#pragma unroll
        for (int d = 16; d >= 1; d >>= 1) e += __shfl_xor(e, d);
        float cm = sj;
#pragma unroll
        for (int d = 16; d >= 1; d >>= 1) cm = fmaxf(cm, __shfl_xor(cm, d));
        float emit_i = Y[((size_t)t * BB + b) * 32 + i];
        float newv = emit_i + mx + __logf(e);
        int mm = x[b * TT + t] > 0;
        __syncthreads();
        if (j == 0) sc[i] = mm ? newv : cm;
        __syncthreads();
    }

    if (tid < 32) {
        float v = sc[tid];
        float mx = v;
#pragma unroll
        for (int d = 16; d >= 1; d >>= 1) mx = fmaxf(mx, __shfl_xor(mx, d));
        float e = __expf(v - mx);
#pragma unroll
        for (int d = 16; d >= 1; d >>= 1) e += __shfl_xor(e, d);
        if (tid == 0) out_pb[b] = (mx + __logf(e)) - goldS;
    }
}

__global__ void final_kernel(const float* __restrict__ out_pb, float* __restrict__ out) {
    if (threadIdx.x == 0 && blockIdx.x == 0) {
        float s = 0.f;
        for (int b = 0; b < BB; ++b) s += out_pb[b];
        out[0] = s / (float)BB;
    }
}

extern "C" void kernel_launch(void* const* d_in, const int* in_sizes, int n_in,
                              void* d_out, int out_size, void* d_ws, size_t ws_size,
                              hipStream_t stream) {
    const int*   x     = (const int*)d_in[0];
    const int*   y0    = (const int*)d_in[1];
    const float* EW    = (const float*)d_in[2];
    const float* Wih0  = (const float*)d_in[3];
    const float* Whh0  = (const float*)d_in[4];
    const float* bih0  = (const float*)d_in[5];
    const float* bhh0  = (const float*)d_in[6];
    const float* Wih1  = (const float*)d_in[7];
    const float* Whh1  = (const float*)d_in[8];
    const float* bih1  = (const float*)d_in[9];
    const float* bhh1  = (const float*)d_in[10];
    const float* Wo    = (const float*)d_in[11];
    const float* bo    = (const float*)d_in[12];
    const float* trans = (const float*)d_in[13];
    const float* h0    = (const float*)d_in[14];
    const float* c0    = (const float*)d_in[15];

    float* ws = (float*)d_ws;
    // Layout (float offsets) — R8-proven:
    //   [0, 524288)            XS bf16 (8192x128); Y fp32(262144)/crfbuf/hglob/bar alias
    //   [524288, 16908288)     Gh: fp16 (2, 8192, 2000)
    //   [16908288, 21102592)   H0 bf16 (8192 x 1024)
    //   [21102592, 29294592)   HSb fp32 (8192 x 1000)
    //   [29294592, 29550592)   Wb0 bf16 (2,2000,128)
    //   [29550592, 31598592)   Wb1 bf16 (2,2000,1024)
    unsigned short* XS = (unsigned short*)ws;
    float* Y      = ws;
    float* crfbuf = ws + 262144;
    unsigned short* hglob = (unsigned short*)(ws + 262160);  // 32,768 bf16
    int*   bar    = (int*)(ws + 262160 + 16384);             // 4,096 ints
    unsigned short* Gh   = (unsigned short*)(ws + 524288);
    unsigned short* H0b  = (unsigned short*)(ws + 16908288);
    float* HSb    = ws + 21102592;
    unsigned short* Wb0  = (unsigned short*)(ws + 29294592);
    unsigned short* Wb1  = (unsigned short*)(ws + 29550592);

    // Phase 1: embedding -> bf16 XS (padded K=128)
    embed_kernel<<<4096, 256, 0, stream>>>(x, EW, XS);

    // Phase 1.5: weight conversion fp32 -> bf16 (padded)
    wconv_kernel<<<(512000 + 255) / 256, 256, 0, stream>>>(Wih0, Wb0, 100, 128, 512000);
    wconv_kernel<<<(4096000 + 255) / 256, 256, 0, stream>>>(Wih1, Wb1, 1000, 1024, 4096000);

    // Phase 2: layer-0 input projections (MFMA, Kpad=128) -> fp16 Gh
    gemm_mfma<<<dim3(64, 32, 2), 256, 0, stream>>>(XS, Wb0, bih0, bhh0, Gh, 128);

    // Phase 2.5: zero hglob + barrier counters; zero pad columns of H0
    zero_kernel<<<(20480 + 255) / 256, 256, 0, stream>>>((int*)hglob, 20480);
    padzero_kernel<<<(98304 + 255) / 256, 256, 0, stream>>>((int*)H0b);

    // Phase 3: layer-0 recurrence -> bf16 H0 (stride 1024)
    {
        int lb = 0, hb = 1;
        int* bar_l = bar;
        void* houtp = (void*)H0b;
        void* args[] = { (void*)&Gh, (void*)&Whh0, (void*)&x, (void*)&h0, (void*)&c0,
                         (void*)&lb, (void*)&houtp, (void*)&hb, (void*)&hglob, (void*)&bar_l };
        hipLaunchCooperativeKernel((void*)rec8_kernel, dim3(32), dim3(256), args, 0, stream);
    }

    // Phase 4: layer-1 input projections (MFMA, Kpad=1024) -> fp16 Gh
    gemm_mfma<<<dim3(64, 32, 2), 256, 0, stream>>>(H0b, Wb1, bih1, bhh1, Gh, 1024);

    // Phase 5: layer-1 recurrence -> fp32 HSb (stride 1000)
    {
        int lb = 2, hb = 0;
        int* bar_l = bar + 2048;
        void* houtp = (void*)HSb;
        void* args[] = { (void*)&Gh, (void*)&Whh1, (void*)&x, (void*)&h0, (void*)&c0,
                         (void*)&lb, (void*)&houtp, (void*)&hb, (void*)&hglob, (void*)&bar_l };
        hipLaunchCooperativeKernel((void*)rec8_kernel, dim3(32), dim3(256), args, 0, stream);
    }

    // Phase 6: output projection (masked)
    outproj_kernel<<<1024, 256, 0, stream>>>(HSb, Wo, bo, x, Y);

    // Phase 7: CRF gold + forward scan
    crf_kernel<<<BB, 1024, 0, stream>>>(Y, x, y0, trans, crfbuf);

    // Phase 8: mean
    final_kernel<<<1, 64, 0, stream>>>(crfbuf, (float*)d_out);
}

// Round 10
// 3657.022 us; speedup vs baseline: 1.3790x; 1.3790x over previous
//
#include <hip/hip_runtime.h>
#include <hip/hip_fp16.h>
#include <math.h>

#define TT 512
#define BB 16
#define EE 100
#define HD 500
#define NEG (-10000.0f)

typedef __attribute__((ext_vector_type(8))) short short8;
typedef __attribute__((ext_vector_type(4))) float f32x4;
typedef __attribute__((ext_vector_type(4))) unsigned int u32x4;

__device__ inline short f2bf(float f) {
    unsigned u = __builtin_bit_cast(unsigned, f);
    unsigned r = (u + 0x7fffu + ((u >> 16) & 1u)) >> 16;
    return (short)r;
}
__device__ inline unsigned short f2h(float f) {
    __half h = __float2half(f);
    return __builtin_bit_cast(unsigned short, h);
}
__device__ inline float h2f(unsigned short u) {
    __half h = __builtin_bit_cast(__half, u);
    return __half2float(h);
}

// ---------------- maxlen: 1 + max t with any x[b,t] > 0 ----------------
__global__ void maxlen_kernel(const int* __restrict__ x, int* __restrict__ out) {
    __shared__ int mx;
    int t = threadIdx.x;          // 512 threads
    if (t == 0) mx = 1;
    __syncthreads();
    int any = 0;
    for (int b = 0; b < BB; ++b) any |= (x[b * TT + t] > 0);
    if (any) atomicMax(&mx, t + 1);
    __syncthreads();
    if (t == 0) out[0] = mx;
}

// ---------------- embedding gather -> bf16 XS (T*B, 128) zero-padded ----------------
__global__ void embed_kernel(const int* __restrict__ x, const float* __restrict__ EW,
                             unsigned short* __restrict__ XS) {
    int idx = blockIdx.x * 256 + threadIdx.x;    // < 8192*128
    int e = idx & 127;
    int r = idx >> 7;          // r = t*16 + b
    int t = r >> 4;
    int b = r & 15;
    unsigned short v = 0;
    if (e < EE) {
        int tok = x[b * TT + t];
        v = (unsigned short)f2bf(EW[(size_t)tok * EE + e]);
    }
    XS[idx] = v;
}

// ---------------- fp32 -> bf16 weight conversion with K padding ----------------
__global__ void wconv_kernel(const float* __restrict__ src, unsigned short* __restrict__ dst,
                             int Ksrc, int Kpad, int total) {
    int i = blockIdx.x * 256 + threadIdx.x;
    if (i >= total) return;
    int r = i / Kpad;
    int k = i - r * Kpad;
    dst[i] = (k < Ksrc) ? (unsigned short)f2bf(src[(size_t)r * Ksrc + k]) : 0;
}

// ---------------- zero scratch (hglob + barriers) ----------------
__global__ void zero_kernel(int* __restrict__ p, int n) {
    int i = blockIdx.x * 256 + threadIdx.x;
    if (i < n) p[i] = 0;
}

// ---------------- zero the pad columns (1000..1023) of bf16 H0 ----------------
__global__ void padzero_kernel(int* __restrict__ p) {
    int i = blockIdx.x * 256 + threadIdx.x;      // < 8192*12
    if (i >= 8192 * 12) return;
    int r = i / 12, c = i - r * 12;
    p[r * 512 + 500 + c] = 0;                    // shorts 1000..1023 = ints 500..511
}

// ------------- bf16 MFMA GEMM: C[z] = f16(A @ W[z]^T + b1[z] + b2[z]) --------------
// A: (8192, Kpad) bf16. W: (2, 2000, Kpad) bf16. C: (2, 8192, 2000) fp16.
__global__ __launch_bounds__(256) void gemm_mfma(
    const unsigned short* __restrict__ A, const unsigned short* __restrict__ W,
    const float* __restrict__ b1, const float* __restrict__ b2,
    unsigned short* __restrict__ C, int Kpad) {
    __shared__ __align__(16) unsigned short AsS[128 * 40];
    __shared__ __align__(16) unsigned short WsS[64 * 40];
    const int tid = threadIdx.x;
    const int lane = tid & 63;
    const int w = tid >> 6;
    const int quad = lane >> 4;
    const int nl = lane & 15;
    const int bm0 = blockIdx.x * 128;
    const int n0 = blockIdx.y * 64;
    const int z = blockIdx.z;

    const unsigned short* Wz = W + (size_t)z * 2000 * Kpad;
    unsigned short* Cz = C + (size_t)z * 8192 * 2000;
    const float* b1z = b1 + (size_t)z * 2000;
    const float* b2z = b2 + (size_t)z * 2000;

    f32x4 acc[2][4];
#pragma unroll
    for (int mt = 0; mt < 2; ++mt)
#pragma unroll
        for (int nt = 0; nt < 4; ++nt) acc[mt][nt] = (f32x4){0.f, 0.f, 0.f, 0.f};

    const int arow = tid >> 2;
    const int kc = tid & 3;
    const int wn = n0 + arow;

    for (int k0 = 0; k0 < Kpad; k0 += 32) {
        short8 av0 = *(const short8*)(A + (size_t)(bm0 + arow) * Kpad + k0 + kc * 8);
        short8 av1 = *(const short8*)(A + (size_t)(bm0 + 64 + arow) * Kpad + k0 + kc * 8);
        short8 wv = {0, 0, 0, 0, 0, 0, 0, 0};
        if (wn < 2000) wv = *(const short8*)(Wz + (size_t)wn * Kpad + k0 + kc * 8);
        __syncthreads();
        *(short8*)&AsS[arow * 40 + kc * 8] = av0;
        *(short8*)&AsS[(64 + arow) * 40 + kc * 8] = av1;
        *(short8*)&WsS[arow * 40 + kc * 8] = wv;
        __syncthreads();

        short8 af[2], bfr[4];
#pragma unroll
        for (int mt = 0; mt < 2; ++mt)
            af[mt] = *(const short8*)&AsS[(w * 32 + mt * 16 + nl) * 40 + quad * 8];
#pragma unroll
        for (int nt = 0; nt < 4; ++nt)
            bfr[nt] = *(const short8*)&WsS[(nt * 16 + nl) * 40 + quad * 8];
#pragma unroll
        for (int mt = 0; mt < 2; ++mt)
#pragma unroll
            for (int nt = 0; nt < 4; ++nt)
                acc[mt][nt] = __builtin_amdgcn_mfma_f32_16x16x32_bf16(
                    af[mt], bfr[nt], acc[mt][nt], 0, 0, 0);
    }

#pragma unroll
    for (int nt = 0; nt < 4; ++nt) {
        int n = n0 + nt * 16 + nl;
        if (n < 2000) {
            float bb = b1z[n] + b2z[n];
#pragma unroll
            for (int mt = 0; mt < 2; ++mt) {
                int mbase = bm0 + w * 32 + mt * 16 + quad * 4;
#pragma unroll
                for (int reg = 0; reg < 4; ++reg)
                    Cz[(size_t)(mbase + reg) * 2000 + n] = f2h(acc[mt][nt][reg] + bb);
            }
        }
    }
}

// ---------------- persistent-weight recurrence, bf16 MFMA, L3-atomic sync ----------
// R7-proven skeleton (all-thread poll, Hout in epilogue). R10 deltas:
// (1) cooperative LDS staging of the 16KB h buffer via 4x global_load_dwordx4
//     sc0 sc1 (L1+L2 bypass -> MALL) with ONE vmcnt(0) -> fully pipelined loads,
//     4x less MALL traffic, much lower VGPR pressure;
// (2) loop bounded by maxlen (bwd starts at t=maxlen-1; all-masked prefix is a
//     no-op on state by construction).
#define NBLK_DIR 16
#define CNT_STRIDE 64

__global__ __launch_bounds__(256, 1) void rec9_kernel(
    const unsigned short* __restrict__ G, const float* __restrict__ Whh,
    const int* __restrict__ x, const float* __restrict__ h0,
    const float* __restrict__ c0, int layerbase,
    void* __restrict__ Houtv, int hbf16,
    unsigned short* __restrict__ hglob, int* __restrict__ bar,
    const int* __restrict__ mlen)
{
    const int blk = blockIdx.x;
    const int dir = blk >> 4;
    const int bsl = blk & 15;
    const int k0 = bsl * 32;
    const int tid = threadIdx.x;
    const int lane = tid & 63;
    const int w = tid >> 6;          // wave 0..3
    const int quad = lane >> 4;      // 0..3
    const int nl = lane & 15;
    const int L = mlen[0];           // 128..512

    const float* Wd = Whh + (size_t)dir * 2000 * HD;
    const unsigned short* Gd = G + (size_t)dir * TT * BB * 2000;
    unsigned short* hgA = hglob + (dir * 2 + 0) * 8192;
    unsigned short* hgB = hglob + (dir * 2 + 1) * 8192;
    int* cntB  = bar + (dir * NBLK_DIR) * CNT_STRIDE;
    int* mycnt = cntB + bsl * CNT_STRIDE;
    const int* myaddr = cntB + (lane & 15) * CNT_STRIDE;

    __shared__ __align__(16) unsigned short hstage[8192];
    __shared__ float sg[4][32][17];

    // ---- load weights into registers as B fragments (bf16) ----
    short8 bf[2][16];
#pragma unroll
    for (int tl = 0; tl < 2; ++tl) {
        int tt = w * 2 + tl;
        int r = tt * 16 + nl;          // 0..127 local gate row
        int g = r >> 5;                // gate 0..3
        int lkr = r & 31;
        int kk = k0 + lkr;             // output h index
        const float* wrow = (kk < HD) ? (Wd + (size_t)(g * HD + kk) * HD) : (const float*)0;
#pragma unroll
        for (int ks = 0; ks < 16; ++ks) {
            int kg0 = ks * 32 + quad * 8;
            short8 v;
            if (wrow && kg0 + 8 <= HD) {
                float4 f0 = *(const float4*)(wrow + kg0);
                float4 f1 = *(const float4*)(wrow + kg0 + 4);
                v[0] = f2bf(f0.x); v[1] = f2bf(f0.y); v[2] = f2bf(f0.z); v[3] = f2bf(f0.w);
                v[4] = f2bf(f1.x); v[5] = f2bf(f1.y); v[6] = f2bf(f1.z); v[7] = f2bf(f1.w);
            } else {
#pragma unroll
                for (int j = 0; j < 8; ++j) {
                    int kg = kg0 + j;
                    float f = (wrow && kg < HD) ? wrow[kg] : 0.f;
                    v[j] = f2bf(f);
                }
            }
            bf[tl][ks] = v;
        }
    }

    // ---- per-thread persistent state: 2 (b,k) pairs, same k different b ----
    const int lk = tid & 31;
    const int k  = k0 + lk;
    const bool kok = (k < HD);
    const int b0v = tid >> 5;          // 0..7
    const int b1v = 8 + (tid >> 5);    // 8..15
    float h_st[2] = {0.f, 0.f}, c_st[2] = {0.f, 0.f};
    if (kok) {
        size_t base0 = (size_t)(layerbase + dir) * BB * HD + (size_t)b0v * HD + k;
        size_t base1 = (size_t)(layerbase + dir) * BB * HD + (size_t)b1v * HD + k;
        h_st[0] = h0[base0]; c_st[0] = c0[base0];
        h_st[1] = h0[base1]; c_st[1] = c0[base1];
    }

    // ---- publish h0 into hgA (packed 8B atomic stores; k>=HD slots stay zeroed) ----
    {
        int i0 = (int)(unsigned short)f2bf(kok ? h_st[0] : 0.f);
        int i1 = (int)(unsigned short)f2bf(kok ? h_st[1] : 0.f);
        int a0 = __shfl_down(i0, 1), c0s = __shfl_down(i0, 2), d0 = __shfl_down(i0, 3);
        int a1 = __shfl_down(i1, 1), c1s = __shfl_down(i1, 2), d1 = __shfl_down(i1, 3);
        if ((lk & 3) == 0 && kok) {
            unsigned long long p0 = (unsigned long long)(unsigned)(i0 | (a0 << 16))
                                  | ((unsigned long long)(unsigned)(c0s | (d0 << 16)) << 32);
            unsigned long long p1 = (unsigned long long)(unsigned)(i1 | (a1 << 16))
                                  | ((unsigned long long)(unsigned)(c1s | (d1 << 16)) << 32);
            int idx0 = bsl * 512 + (b0v + 16 * (lk >> 3)) * 8 + (lk & 7);
            int idx1 = bsl * 512 + (b1v + 16 * (lk >> 3)) * 8 + (lk & 7);
            __hip_atomic_store((unsigned long long*)(hgA + idx0), p0,
                               __ATOMIC_RELAXED, __HIP_MEMORY_SCOPE_AGENT);
            __hip_atomic_store((unsigned long long*)(hgA + idx1), p1,
                               __ATOMIC_RELAXED, __HIP_MEMORY_SCOPE_AGENT);
        }
    }

    // ---- init barrier (R7 style) ----
    __threadfence_block();
    __syncthreads();
    if (tid == 0)
        __hip_atomic_fetch_add(mycnt, 1, __ATOMIC_RELAXED, __HIP_MEMORY_SCOPE_AGENT);
    while (!__all(__hip_atomic_load(myaddr, __ATOMIC_RELAXED, __HIP_MEMORY_SCOPE_AGENT) >= 1)) { }

    // ---- prefetch step-0 G (raw) + mask ----
    unsigned short gpraw[2][4]; int m[2];
    m[0] = m[1] = 0;
    gpraw[0][0]=gpraw[0][1]=gpraw[0][2]=gpraw[0][3]=0;
    gpraw[1][0]=gpraw[1][1]=gpraw[1][2]=gpraw[1][3]=0;
    {
        int t = dir ? (L - 1) : 0;
        if (kok) {
            const unsigned short* gr0 = Gd + ((size_t)t * BB + b0v) * 2000 + k;
            const unsigned short* gr1 = Gd + ((size_t)t * BB + b1v) * 2000 + k;
            gpraw[0][0] = gr0[0]; gpraw[0][1] = gr0[HD]; gpraw[0][2] = gr0[2 * HD]; gpraw[0][3] = gr0[3 * HD];
            gpraw[1][0] = gr1[0]; gpraw[1][1] = gr1[HD]; gpraw[1][2] = gr1[2 * HD]; gpraw[1][3] = gr1[3 * HD];
            m[0] = x[b0v * TT + t] > 0;
            m[1] = x[b1v * TT + t] > 0;
        }
    }

    for (int s = 0; s < L; ++s) {
        const int t = dir ? (L - 1 - s) : s;
        const unsigned short* hr = (s & 1) ? hgB : hgA;
        unsigned short* hw = (s & 1) ? hgA : hgB;

        // ---- cooperative stage hr (16KB) into LDS: 4x16B per thread, L1+L2 bypass,
        //      single vmcnt wait -> fully pipelined ----
        {
            const unsigned short* p0 = hr + (tid +   0) * 8;
            const unsigned short* p1 = hr + (tid + 256) * 8;
            const unsigned short* p2 = hr + (tid + 512) * 8;
            const unsigned short* p3 = hr + (tid + 768) * 8;
            u32x4 c0v, c1v, c2v, c3v;
            asm volatile(
                "global_load_dwordx4 %0, %4, off sc0 sc1\n\t"
                "global_load_dwordx4 %1, %5, off sc0 sc1\n\t"
                "global_load_dwordx4 %2, %6, off sc0 sc1\n\t"
                "global_load_dwordx4 %3, %7, off sc0 sc1\n\t"
                "s_waitcnt vmcnt(0)"
                : "=&v"(c0v), "=&v"(c1v), "=&v"(c2v), "=&v"(c3v)
                : "v"(p0), "v"(p1), "v"(p2), "v"(p3)
                : "memory");
            *(u32x4*)&hstage[(tid +   0) * 8] = c0v;
            *(u32x4*)&hstage[(tid + 256) * 8] = c1v;
            *(u32x4*)&hstage[(tid + 512) * 8] = c2v;
            *(u32x4*)&hstage[(tid + 768) * 8] = c3v;
        }
        __syncthreads();

        // ---- recurrent preactivation via MFMA (A fragments from LDS) ----
        f32x4 acc0 = {0.f, 0.f, 0.f, 0.f};
        f32x4 acc1 = {0.f, 0.f, 0.f, 0.f};
#pragma unroll
        for (int ks = 0; ks < 16; ++ks) {
            short8 a = *(const short8*)&hstage[ks * 512 + lane * 8];
            acc0 = __builtin_amdgcn_mfma_f32_16x16x32_bf16(a, bf[0][ks], acc0, 0, 0, 0);
            acc1 = __builtin_amdgcn_mfma_f32_16x16x32_bf16(a, bf[1][ks], acc1, 0, 0, 0);
        }

        // ---- scatter D to LDS: sg[gate][lk][b] ----
        {
            int r0 = (w * 2 + 0) * 16 + nl;
            int r1 = (w * 2 + 1) * 16 + nl;
            int g0r = r0 >> 5, lk0 = r0 & 31;
            int g1r = r1 >> 5, lk1 = r1 & 31;
#pragma unroll
            for (int reg = 0; reg < 4; ++reg) {
                int b = quad * 4 + reg;
                sg[g0r][lk0][b] = acc0[reg];
                sg[g1r][lk1][b] = acc1[reg];
            }
        }
        __syncthreads();

        // ---- epilogue: gates, state update, Hout (R7 placement) ----
        if (kok) {
#pragma unroll
            for (int p = 0; p < 2; ++p) {
                int b = p ? b1v : b0v;
                float si  = sg[0][lk][b] + h2f(gpraw[p][0]);
                float sf  = sg[1][lk][b] + h2f(gpraw[p][1]);
                float sgg = sg[2][lk][b] + h2f(gpraw[p][2]);
                float so  = sg[3][lk][b] + h2f(gpraw[p][3]);
                float ig = 1.f / (1.f + __expf(-si));
                float fg = 1.f / (1.f + __expf(-sf));
                float gg = tanhf(sgg);
                float og = 1.f / (1.f + __expf(-so));
                float c_new = fg * c_st[p] + ig * gg;
                float h_new = og * tanhf(c_new);
                float hn = m[p] ? h_new : h_st[p];
                float cn = m[p] ? c_new : c_st[p];
                h_st[p] = hn; c_st[p] = cn;
                float outv = m[p] ? h_new : 0.f;
                if (hbf16)
                    ((unsigned short*)Houtv)[((size_t)t * BB + b) * 1024 + dir * HD + k] =
                        (unsigned short)f2bf(outv);
                else
                    ((float*)Houtv)[((size_t)t * BB + b) * 1000 + dir * HD + k] = outv;
            }
        }

        // ---- publish h into hw (packed 8B atomic stores) ----
        {
            int i0 = (int)(unsigned short)f2bf(kok ? h_st[0] : 0.f);
            int i1 = (int)(unsigned short)f2bf(kok ? h_st[1] : 0.f);
            int a0 = __shfl_down(i0, 1), c0s = __shfl_down(i0, 2), d0 = __shfl_down(i0, 3);
            int a1 = __shfl_down(i1, 1), c1s = __shfl_down(i1, 2), d1 = __shfl_down(i1, 3);
            if ((lk & 3) == 0 && kok) {
                unsigned long long p0 = (unsigned long long)(unsigned)(i0 | (a0 << 16))
                                      | ((unsigned long long)(unsigned)(c0s | (d0 << 16)) << 32);
                unsigned long long p1 = (unsigned long long)(unsigned)(i1 | (a1 << 16))
                                      | ((unsigned long long)(unsigned)(c1s | (d1 << 16)) << 32);
                int idx0 = bsl * 512 + (b0v + 16 * (lk >> 3)) * 8 + (lk & 7);
                int idx1 = bsl * 512 + (b1v + 16 * (lk >> 3)) * 8 + (lk & 7);
                __hip_atomic_store((unsigned long long*)(hw + idx0), p0,
                                   __ATOMIC_RELAXED, __HIP_MEMORY_SCOPE_AGENT);
                __hip_atomic_store((unsigned long long*)(hw + idx1), p1,
                                   __ATOMIC_RELAXED, __HIP_MEMORY_SCOPE_AGENT);
            }
        }

        if (s + 1 < L) {
            // ---- drain stores, bump counter ----
            __threadfence_block();
            __syncthreads();
            if (tid == 0)
                __hip_atomic_fetch_add(mycnt, 1, __ATOMIC_RELAXED, __HIP_MEMORY_SCOPE_AGENT);

            // ---- prefetch next step's G (raw) + mask: overlaps the poll below ----
            int tn = dir ? (L - 2 - s) : (s + 1);
            if (kok) {
                const unsigned short* gr0 = Gd + ((size_t)tn * BB + b0v) * 2000 + k;
                const unsigned short* gr1 = Gd + ((size_t)tn * BB + b1v) * 2000 + k;
                gpraw[0][0] = gr0[0]; gpraw[0][1] = gr0[HD]; gpraw[0][2] = gr0[2 * HD]; gpraw[0][3] = gr0[3 * HD];
                gpraw[1][0] = gr1[0]; gpraw[1][1] = gr1[HD]; gpraw[1][2] = gr1[2 * HD]; gpraw[1][3] = gr1[3 * HD];
                m[0] = x[b0v * TT + tn] > 0;
                m[1] = x[b1v * TT + tn] > 0;
            }

            // ---- poll: all threads, all 16 counters in parallel (R7 style) ----
            while (!__all(__hip_atomic_load(myaddr, __ATOMIC_RELAXED,
                                            __HIP_MEMORY_SCOPE_AGENT) >= s + 2)) { }
        }
    }
}

// ---------------- output projection: Y (T,B,32) = HS @ Wo^T + bo, masked ------------
__global__ void outproj_kernel(const float* __restrict__ HS, const float* __restrict__ Wo,
                               const float* __restrict__ bo, const int* __restrict__ x,
                               float* __restrict__ Y) {
    int idx = blockIdx.x * 256 + threadIdx.x;
    int r = idx >> 5;
    int n = idx & 31;
    int t = r >> 4;
    int b = r & 15;
    float out = 0.f;
    if (x[b * TT + t] > 0) {
        const float4* h4 = (const float4*)(HS + (size_t)r * 1000);
        const float4* w4 = (const float4*)(Wo + (size_t)n * 1000);
        float s = 0.f;
#pragma unroll 4
        for (int q = 0; q < 250; ++q) {
            float4 a = h4[q]; float4 w = w4[q];
            s += a.x * w.x + a.y * w.y + a.z * w.z + a.w * w.w;
        }
        out = s + bo[n];
    }
    Y[idx] = out;
}

// ---------------- CRF: gold score + forward scan ----------------
__global__ __launch_bounds__(1024) void crf_kernel(
    const float* __restrict__ Y, const int* __restrict__ x, const int* __restrict__ y0,
    const float* __restrict__ trans, float* __restrict__ out_pb) {
    int b = blockIdx.x;
    int tid = threadIdx.x;
    int i = tid >> 5;
    int j = tid & 31;
    float tr_ij = trans[i * 32 + j];

    __shared__ float sc[32];
    __shared__ float wred[16];
    __shared__ float goldS;

    float gp = 0.f;
    if (tid < TT) {
        int t = tid;
        int xm = x[b * TT + t];
        float mf = (xm > 0) ? 1.f : 0.f;
        int ynext = y0[b * TT + t];
        int yprev = (t == 0) ? 1 : y0[b * TT + t - 1];
        gp = Y[((size_t)t * BB + b) * 32 + ynext] + trans[ynext * 32 + yprev] * mf;
    }
#pragma unroll
    for (int d = 32; d >= 1; d >>= 1) gp += __shfl_down(gp, d);
    if ((tid & 63) == 0) wred[tid >> 6] = gp;
    __syncthreads();
    if (tid == 0) {
        float s = 0.f;
        for (int ww = 0; ww < 16; ++ww) s += wred[ww];
        goldS = s;
    }
    if (tid < 32) sc[tid] = (tid == 1) ? 0.f : NEG;
    __syncthreads();

    for (int t = 0; t < TT; ++t) {
        float sj = sc[j];
        float z = sj + tr_ij;
        float mx = z;
#pragma unroll
        for (int d = 16; d >= 1; d >>= 1) mx = fmaxf(mx, __shfl_xor(mx, d));
        float e = __expf(z - mx);
#pragma unroll
        for (int d = 16; d >= 1; d >>= 1) e += __shfl_xor(e, d);
        float cm = sj;
#pragma unroll
        for (int d = 16; d >= 1; d >>= 1) cm = fmaxf(cm, __shfl_xor(cm, d));
        float emit_i = Y[((size_t)t * BB + b) * 32 + i];
        float newv = emit_i + mx + __logf(e);
        int mm = x[b * TT + t] > 0;
        __syncthreads();
        if (j == 0) sc[i] = mm ? newv : cm;
        __syncthreads();
    }

    if (tid < 32) {
        float v = sc[tid];
        float mx = v;
#pragma unroll
        for (int d = 16; d >= 1; d >>= 1) mx = fmaxf(mx, __shfl_xor(mx, d));
        float e = __expf(v - mx);
#pragma unroll
        for (int d = 16; d >= 1; d >>= 1) e += __shfl_xor(e, d);
        if (tid == 0) out_pb[b] = (mx + __logf(e)) - goldS;
    }
}

__global__ void final_kernel(const float* __restrict__ out_pb, float* __restrict__ out) {
    if (threadIdx.x == 0 && blockIdx.x == 0) {
        float s = 0.f;
        for (int b = 0; b < BB; ++b) s += out_pb[b];
        out[0] = s / (float)BB;
    }
}

extern "C" void kernel_launch(void* const* d_in, const int* in_sizes, int n_in,
                              void* d_out, int out_size, void* d_ws, size_t ws_size,
                              hipStream_t stream) {
    const int*   x     = (const int*)d_in[0];
    const int*   y0    = (const int*)d_in[1];
    const float* EW    = (const float*)d_in[2];
    const float* Wih0  = (const float*)d_in[3];
    const float* Whh0  = (const float*)d_in[4];
    const float* bih0  = (const float*)d_in[5];
    const float* bhh0  = (const float*)d_in[6];
    const float* Wih1  = (const float*)d_in[7];
    const float* Whh1  = (const float*)d_in[8];
    const float* bih1  = (const float*)d_in[9];
    const float* bhh1  = (const float*)d_in[10];
    const float* Wo    = (const float*)d_in[11];
    const float* bo    = (const float*)d_in[12];
    const float* trans = (const float*)d_in[13];
    const float* h0    = (const float*)d_in[14];
    const float* c0    = (const float*)d_in[15];

    float* ws = (float*)d_ws;
    // Layout (float offsets) — R8-proven + mlen:
    //   [0, 524288)            XS bf16 (8192x128); Y fp32(262144)/crfbuf/hglob/bar alias
    //   [524288, 16908288)     Gh: fp16 (2, 8192, 2000)
    //   [16908288, 21102592)   H0 bf16 (8192 x 1024)
    //   [21102592, 29294592)   HSb fp32 (8192 x 1000)
    //   [29294592, 29550592)   Wb0 bf16 (2,2000,128)
    //   [29550592, 31598592)   Wb1 bf16 (2,2000,1024)
    //   [31598592]             mlen (1 int) — outside XS alias region
    unsigned short* XS = (unsigned short*)ws;
    float* Y      = ws;
    float* crfbuf = ws + 262144;
    unsigned short* hglob = (unsigned short*)(ws + 262160);  // 32,768 bf16
    int*   bar    = (int*)(ws + 262160 + 16384);             // 4,096 ints
    unsigned short* Gh   = (unsigned short*)(ws + 524288);
    unsigned short* H0b  = (unsigned short*)(ws + 16908288);
    float* HSb    = ws + 21102592;
    unsigned short* Wb0  = (unsigned short*)(ws + 29294592);
    unsigned short* Wb1  = (unsigned short*)(ws + 29550592);
    int* mlen     = (int*)(ws + 31598592);

    // Phase 0: maxlen (outside XS region — safe to run first)
    maxlen_kernel<<<1, 512, 0, stream>>>(x, mlen);

    // Phase 1: embedding -> bf16 XS (padded K=128)
    embed_kernel<<<4096, 256, 0, stream>>>(x, EW, XS);

    // Phase 1.5: weight conversion fp32 -> bf16 (padded)
    wconv_kernel<<<(512000 + 255) / 256, 256, 0, stream>>>(Wih0, Wb0, 100, 128, 512000);
    wconv_kernel<<<(4096000 + 255) / 256, 256, 0, stream>>>(Wih1, Wb1, 1000, 1024, 4096000);

    // Phase 2: layer-0 input projections (MFMA, Kpad=128) -> fp16 Gh
    gemm_mfma<<<dim3(64, 32, 2), 256, 0, stream>>>(XS, Wb0, bih0, bhh0, Gh, 128);

    // Phase 2.5: zero hglob + barrier counters; zero pad columns of H0
    zero_kernel<<<(20480 + 255) / 256, 256, 0, stream>>>((int*)hglob, 20480);
    padzero_kernel<<<(98304 + 255) / 256, 256, 0, stream>>>((int*)H0b);

    // Phase 3: layer-0 recurrence -> bf16 H0 (stride 1024)
    {
        int lb = 0, hb = 1;
        int* bar_l = bar;
        void* houtp = (void*)H0b;
        void* args[] = { (void*)&Gh, (void*)&Whh0, (void*)&x, (void*)&h0, (void*)&c0,
                         (void*)&lb, (void*)&houtp, (void*)&hb, (void*)&hglob, (void*)&bar_l,
                         (void*)&mlen };
        hipLaunchCooperativeKernel((void*)rec9_kernel, dim3(32), dim3(256), args, 0, stream);
    }

    // Phase 4: layer-1 input projections (MFMA, Kpad=1024) -> fp16 Gh
    // (rows t>=maxlen of H0b are never read downstream: rec9 L1 reads t<maxlen only)
    gemm_mfma<<<dim3(64, 32, 2), 256, 0, stream>>>(H0b, Wb1, bih1, bhh1, Gh, 1024);

    // Phase 5: layer-1 recurrence -> fp32 HSb (stride 1000)
    {
        int lb = 2, hb = 0;
        int* bar_l = bar + 2048;
        void* houtp = (void*)HSb;
        void* args[] = { (void*)&Gh, (void*)&Whh1, (void*)&x, (void*)&h0, (void*)&c0,
                         (void*)&lb, (void*)&houtp, (void*)&hb, (void*)&hglob, (void*)&bar_l,
                         (void*)&mlen };
        hipLaunchCooperativeKernel((void*)rec9_kernel, dim3(32), dim3(256), args, 0, stream);
    }

    // Phase 6: output projection (masked; rows t>=maxlen masked to 0 by x)
    outproj_kernel<<<1024, 256, 0, stream>>>(HSb, Wo, bo, x, Y);

    // Phase 7: CRF gold + forward scan
    crf_kernel<<<BB, 1024, 0, stream>>>(Y, x, y0, trans, crfbuf);

    // Phase 8: mean
    final_kernel<<<1, 64, 0, stream>>>(crfbuf, (float*)d_out);
}

// Round 11
// 3127.048 us; speedup vs baseline: 1.6128x; 1.1695x over previous
//
#include <hip/hip_runtime.h>
#include <hip/hip_fp16.h>
#include <math.h>

#define TT 512
#define BB 16
#define EE 100
#define HD 500
#define NEG (-10000.0f)
#define SENT64 0xFFFFFFFFFFFFFFFFull
#define SENT32 0xFFFFFFFFu

typedef __attribute__((ext_vector_type(8))) short short8;
typedef __attribute__((ext_vector_type(4))) float f32x4;
typedef __attribute__((ext_vector_type(4))) unsigned int u32x4;

__device__ inline short f2bf(float f) {
    unsigned u = __builtin_bit_cast(unsigned, f);
    unsigned r = (u + 0x7fffu + ((u >> 16) & 1u)) >> 16;
    return (short)r;
}
__device__ inline unsigned short f2h(float f) {
    __half h = __float2half(f);
    return __builtin_bit_cast(unsigned short, h);
}
__device__ inline float h2f(unsigned short u) {
    __half h = __builtin_bit_cast(__half, u);
    return __half2float(h);
}
__device__ inline float bf2f(unsigned short u) {
    return __builtin_bit_cast(float, ((unsigned)u) << 16);
}

// ---------------- maxlen: 1 + max t with any x[b,t] > 0 ----------------
__global__ void maxlen_kernel(const int* __restrict__ x, int* __restrict__ out) {
    __shared__ int mx;
    int t = threadIdx.x;          // 512 threads
    if (t == 0) mx = 1;
    __syncthreads();
    int any = 0;
    for (int b = 0; b < BB; ++b) any |= (x[b * TT + t] > 0);
    if (any) atomicMax(&mx, t + 1);
    __syncthreads();
    if (t == 0) out[0] = mx;
}

// ---------------- sentinel fill via agent-scope atomic stores (MALL-visible) -------
__global__ void sentfill_kernel(unsigned long long* __restrict__ p, int n) {
    int i = blockIdx.x * 256 + threadIdx.x;
    if (i < n)
        __hip_atomic_store(p + i, SENT64, __ATOMIC_RELAXED, __HIP_MEMORY_SCOPE_AGENT);
}

// ---------------- embedding gather -> bf16 XS (T*B, 128) zero-padded ----------------
__global__ void embed_kernel(const int* __restrict__ x, const float* __restrict__ EW,
                             unsigned short* __restrict__ XS) {
    int idx = blockIdx.x * 256 + threadIdx.x;    // < 8192*128
    int e = idx & 127;
    int r = idx >> 7;          // r = t*16 + b
    int t = r >> 4;
    int b = r & 15;
    unsigned short v = 0;
    if (e < EE) {
        int tok = x[b * TT + t];
        v = (unsigned short)f2bf(EW[(size_t)tok * EE + e]);
    }
    XS[idx] = v;
}

// ---------------- fp32 -> bf16 weight conversion with K padding ----------------
__global__ void wconv_kernel(const float* __restrict__ src, unsigned short* __restrict__ dst,
                             int Ksrc, int Kpad, int total) {
    int i = blockIdx.x * 256 + threadIdx.x;
    if (i >= total) return;
    int r = i / Kpad;
    int k = i - r * Kpad;
    dst[i] = (k < Ksrc) ? (unsigned short)f2bf(src[(size_t)r * Ksrc + k]) : 0;
}

// ---------------- zero the pad columns (1000..1023) of bf16 H0 ----------------
__global__ void padzero_kernel(int* __restrict__ p) {
    int i = blockIdx.x * 256 + threadIdx.x;      // < 8192*12
    if (i >= 8192 * 12) return;
    int r = i / 12, c = i - r * 12;
    p[r * 512 + 500 + c] = 0;                    // shorts 1000..1023 = ints 500..511
}

// ------------- bf16 MFMA GEMM: C[z] = f16(A @ W[z]^T + b1[z] + b2[z]) --------------
// A: (8192, Kpad) bf16. W: (2, 2000, Kpad) bf16. C: (2, 8192, 2000) fp16.
__global__ __launch_bounds__(256) void gemm_mfma(
    const unsigned short* __restrict__ A, const unsigned short* __restrict__ W,
    const float* __restrict__ b1, const float* __restrict__ b2,
    unsigned short* __restrict__ C, int Kpad) {
    __shared__ __align__(16) unsigned short AsS[128 * 40];
    __shared__ __align__(16) unsigned short WsS[64 * 40];
    const int tid = threadIdx.x;
    const int lane = tid & 63;
    const int w = tid >> 6;
    const int quad = lane >> 4;
    const int nl = lane & 15;
    const int bm0 = blockIdx.x * 128;
    const int n0 = blockIdx.y * 64;
    const int z = blockIdx.z;

    const unsigned short* Wz = W + (size_t)z * 2000 * Kpad;
    unsigned short* Cz = C + (size_t)z * 8192 * 2000;
    const float* b1z = b1 + (size_t)z * 2000;
    const float* b2z = b2 + (size_t)z * 2000;

    f32x4 acc[2][4];
#pragma unroll
    for (int mt = 0; mt < 2; ++mt)
#pragma unroll
        for (int nt = 0; nt < 4; ++nt) acc[mt][nt] = (f32x4){0.f, 0.f, 0.f, 0.f};

    const int arow = tid >> 2;
    const int kc = tid & 3;
    const int wn = n0 + arow;

    for (int k0 = 0; k0 < Kpad; k0 += 32) {
        short8 av0 = *(const short8*)(A + (size_t)(bm0 + arow) * Kpad + k0 + kc * 8);
        short8 av1 = *(const short8*)(A + (size_t)(bm0 + 64 + arow) * Kpad + k0 + kc * 8);
        short8 wv = {0, 0, 0, 0, 0, 0, 0, 0};
        if (wn < 2000) wv = *(const short8*)(Wz + (size_t)wn * Kpad + k0 + kc * 8);
        __syncthreads();
        *(short8*)&AsS[arow * 40 + kc * 8] = av0;
        *(short8*)&AsS[(64 + arow) * 40 + kc * 8] = av1;
        *(short8*)&WsS[arow * 40 + kc * 8] = wv;
        __syncthreads();

        short8 af[2], bfr[4];
#pragma unroll
        for (int mt = 0; mt < 2; ++mt)
            af[mt] = *(const short8*)&AsS[(w * 32 + mt * 16 + nl) * 40 + quad * 8];
#pragma unroll
        for (int nt = 0; nt < 4; ++nt)
            bfr[nt] = *(const short8*)&WsS[(nt * 16 + nl) * 40 + quad * 8];
#pragma unroll
        for (int mt = 0; mt < 2; ++mt)
#pragma unroll
            for (int nt = 0; nt < 4; ++nt)
                acc[mt][nt] = __builtin_amdgcn_mfma_f32_16x16x32_bf16(
                    af[mt], bfr[nt], acc[mt][nt], 0, 0, 0);
    }

#pragma unroll
    for (int nt = 0; nt < 4; ++nt) {
        int n = n0 + nt * 16 + nl;
        if (n < 2000) {
            float bb = b1z[n] + b2z[n];
#pragma unroll
            for (int mt = 0; mt < 2; ++mt) {
                int mbase = bm0 + w * 32 + mt * 16 + quad * 4;
#pragma unroll
                for (int reg = 0; reg < 4; ++reg)
                    Cz[(size_t)(mbase + reg) * 2000 + n] = f2h(acc[mt][nt][reg] + bb);
            }
        }
    }
}

// ---------------- persistent-weight recurrence, bf16 MFMA, DATA-IS-FLAG sync -------
// hseq: per dir, (TT+1) write-once buffers of 8192 bf16 in MFMA-A layout, pre-filled
// with 0xFFFF sentinels via agent-scope atomic stores. Producer at step s publishes
// buf[s+1] with 8B agent-scope atomic stores (ALL slots, zeros for k>=HD). Consumer
// stages buf[s] into LDS with sc0/sc1 dwordx4 loads, retrying any 4B word that still
// reads 0xFFFFFFFF (two bf16 NaNs — unreachable from f2bf of finite h). Stale reads
// can only return SENT (write-once buffers) -> retry, never wrong data. No fences,
// no barriers, no counters.
__global__ __launch_bounds__(256, 1) void rec10_kernel(
    const unsigned short* __restrict__ G, const float* __restrict__ Whh,
    const int* __restrict__ x, const float* __restrict__ h0,
    const float* __restrict__ c0, int layerbase,
    unsigned short* __restrict__ Hout, unsigned short* __restrict__ hseq,
    const int* __restrict__ mlen)
{
    const int blk = blockIdx.x;
    const int dir = blk >> 4;
    const int bsl = blk & 15;
    const int k0 = bsl * 32;
    const int tid = threadIdx.x;
    const int lane = tid & 63;
    const int w = tid >> 6;          // wave 0..3
    const int quad = lane >> 4;      // 0..3
    const int nl = lane & 15;
    const int L = mlen[0];           // 1..512

    const float* Wd = Whh + (size_t)dir * 2000 * HD;
    const unsigned short* Gd = G + (size_t)dir * TT * BB * 2000;
    unsigned short* hdir = hseq + (size_t)dir * (TT + 1) * 8192;

    __shared__ __align__(16) unsigned short hstage[8192];
    __shared__ float sg[4][32][17];

    // ---- load weights into registers as B fragments (bf16) ----
    short8 bf[2][16];
#pragma unroll
    for (int tl = 0; tl < 2; ++tl) {
        int tt = w * 2 + tl;
        int r = tt * 16 + nl;          // 0..127 local gate row
        int g = r >> 5;                // gate 0..3
        int lkr = r & 31;
        int kk = k0 + lkr;             // output h index
        const float* wrow = (kk < HD) ? (Wd + (size_t)(g * HD + kk) * HD) : (const float*)0;
#pragma unroll
        for (int ks = 0; ks < 16; ++ks) {
            int kg0 = ks * 32 + quad * 8;
            short8 v;
            if (wrow && kg0 + 8 <= HD) {
                float4 f0 = *(const float4*)(wrow + kg0);
                float4 f1 = *(const float4*)(wrow + kg0 + 4);
                v[0] = f2bf(f0.x); v[1] = f2bf(f0.y); v[2] = f2bf(f0.z); v[3] = f2bf(f0.w);
                v[4] = f2bf(f1.x); v[5] = f2bf(f1.y); v[6] = f2bf(f1.z); v[7] = f2bf(f1.w);
            } else {
#pragma unroll
                for (int j = 0; j < 8; ++j) {
                    int kg = kg0 + j;
                    float f = (wrow && kg < HD) ? wrow[kg] : 0.f;
                    v[j] = f2bf(f);
                }
            }
            bf[tl][ks] = v;
        }
    }

    // ---- per-thread persistent state: 2 (b,k) pairs, same k different b ----
    const int lk = tid & 31;
    const int k  = k0 + lk;
    const bool kok = (k < HD);
    const int b0v = tid >> 5;          // 0..7
    const int b1v = 8 + (tid >> 5);    // 8..15
    float h_st[2] = {0.f, 0.f}, c_st[2] = {0.f, 0.f};
    if (kok) {
        size_t base0 = (size_t)(layerbase + dir) * BB * HD + (size_t)b0v * HD + k;
        size_t base1 = (size_t)(layerbase + dir) * BB * HD + (size_t)b1v * HD + k;
        h_st[0] = h0[base0]; c_st[0] = c0[base0];
        h_st[1] = h0[base1]; c_st[1] = c0[base1];
    }

    // ---- publish h0 into buf[0] (ALL slots: zeros for k>=HD; 8B atomic stores) ----
    {
        int i0 = (int)(unsigned short)f2bf(kok ? h_st[0] : 0.f);
        int i1 = (int)(unsigned short)f2bf(kok ? h_st[1] : 0.f);
        int a0 = __shfl_down(i0, 1), c0s = __shfl_down(i0, 2), d0 = __shfl_down(i0, 3);
        int a1 = __shfl_down(i1, 1), c1s = __shfl_down(i1, 2), d1 = __shfl_down(i1, 3);
        if ((lk & 3) == 0) {
            unsigned long long p0 = (unsigned long long)(unsigned)(i0 | (a0 << 16))
                                  | ((unsigned long long)(unsigned)(c0s | (d0 << 16)) << 32);
            unsigned long long p1 = (unsigned long long)(unsigned)(i1 | (a1 << 16))
                                  | ((unsigned long long)(unsigned)(c1s | (d1 << 16)) << 32);
            int idx0 = bsl * 512 + (b0v + 16 * (lk >> 3)) * 8 + (lk & 7);
            int idx1 = bsl * 512 + (b1v + 16 * (lk >> 3)) * 8 + (lk & 7);
            __hip_atomic_store((unsigned long long*)(hdir + idx0), p0,
                               __ATOMIC_RELAXED, __HIP_MEMORY_SCOPE_AGENT);
            __hip_atomic_store((unsigned long long*)(hdir + idx1), p1,
                               __ATOMIC_RELAXED, __HIP_MEMORY_SCOPE_AGENT);
        }
    }

    // ---- prefetch step-0 G (raw) + mask ----
    unsigned short gpraw[2][4]; int m[2];
    m[0] = m[1] = 0;
    gpraw[0][0]=gpraw[0][1]=gpraw[0][2]=gpraw[0][3]=0;
    gpraw[1][0]=gpraw[1][1]=gpraw[1][2]=gpraw[1][3]=0;
    {
        int t = dir ? (L - 1) : 0;
        if (kok) {
            const unsigned short* gr0 = Gd + ((size_t)t * BB + b0v) * 2000 + k;
            const unsigned short* gr1 = Gd + ((size_t)t * BB + b1v) * 2000 + k;
            gpraw[0][0] = gr0[0]; gpraw[0][1] = gr0[HD]; gpraw[0][2] = gr0[2 * HD]; gpraw[0][3] = gr0[3 * HD];
            gpraw[1][0] = gr1[0]; gpraw[1][1] = gr1[HD]; gpraw[1][2] = gr1[2 * HD]; gpraw[1][3] = gr1[3 * HD];
            m[0] = x[b0v * TT + t] > 0;
            m[1] = x[b1v * TT + t] > 0;
        }
    }

    for (int s = 0; s < L; ++s) {
        const int t = dir ? (L - 1 - s) : s;
        const unsigned short* bufr = hdir + (size_t)s * 8192;
        unsigned short* bufw = hdir + (size_t)(s + 1) * 8192;

        // ---- poll-stage buf[s] into LDS: per-thread 4x16B sc0/sc1 loads, retry
        //      until no 4B word is the sentinel (data-is-flag) ----
        {
            const unsigned short* p0 = bufr + (tid +   0) * 8;
            const unsigned short* p1 = bufr + (tid + 256) * 8;
            const unsigned short* p2 = bufr + (tid + 512) * 8;
            const unsigned short* p3 = bufr + (tid + 768) * 8;
            u32x4 c0v, c1v, c2v, c3v;
            for (;;) {
                asm volatile(
                    "global_load_dwordx4 %0, %4, off sc0 sc1\n\t"
                    "global_load_dwordx4 %1, %5, off sc0 sc1\n\t"
                    "global_load_dwordx4 %2, %6, off sc0 sc1\n\t"
                    "global_load_dwordx4 %3, %7, off sc0 sc1\n\t"
                    "s_waitcnt vmcnt(0)"
                    : "=&v"(c0v), "=&v"(c1v), "=&v"(c2v), "=&v"(c3v)
                    : "v"(p0), "v"(p1), "v"(p2), "v"(p3)
                    : "memory");
                unsigned bad = 0;
#pragma unroll
                for (int q = 0; q < 4; ++q)
                    bad |= (c0v[q] == SENT32) | (c1v[q] == SENT32)
                         | (c2v[q] == SENT32) | (c3v[q] == SENT32);
                if (!bad) break;
            }
            *(u32x4*)&hstage[(tid +   0) * 8] = c0v;
            *(u32x4*)&hstage[(tid + 256) * 8] = c1v;
            *(u32x4*)&hstage[(tid + 512) * 8] = c2v;
            *(u32x4*)&hstage[(tid + 768) * 8] = c3v;
        }
        __syncthreads();

        // ---- recurrent preactivation via MFMA (A fragments from LDS) ----
        f32x4 acc0 = {0.f, 0.f, 0.f, 0.f};
        f32x4 acc1 = {0.f, 0.f, 0.f, 0.f};
#pragma unroll
        for (int ks = 0; ks < 16; ++ks) {
            short8 a = *(const short8*)&hstage[ks * 512 + lane * 8];
            acc0 = __builtin_amdgcn_mfma_f32_16x16x32_bf16(a, bf[0][ks], acc0, 0, 0, 0);
            acc1 = __builtin_amdgcn_mfma_f32_16x16x32_bf16(a, bf[1][ks], acc1, 0, 0, 0);
        }

        // ---- scatter D to LDS: sg[gate][lk][b] ----
        {
            int r0 = (w * 2 + 0) * 16 + nl;
            int r1 = (w * 2 + 1) * 16 + nl;
            int g0r = r0 >> 5, lk0 = r0 & 31;
            int g1r = r1 >> 5, lk1 = r1 & 31;
#pragma unroll
            for (int reg = 0; reg < 4; ++reg) {
                int b = quad * 4 + reg;
                sg[g0r][lk0][b] = acc0[reg];
                sg[g1r][lk1][b] = acc1[reg];
            }
        }
        __syncthreads();

        // ---- epilogue: gates, state update, Hout (bf16, stride 1024) ----
        if (kok) {
#pragma unroll
            for (int p = 0; p < 2; ++p) {
                int b = p ? b1v : b0v;
                float si  = sg[0][lk][b] + h2f(gpraw[p][0]);
                float sf  = sg[1][lk][b] + h2f(gpraw[p][1]);
                float sgg = sg[2][lk][b] + h2f(gpraw[p][2]);
                float so  = sg[3][lk][b] + h2f(gpraw[p][3]);
                float ig = 1.f / (1.f + __expf(-si));
                float fg = 1.f / (1.f + __expf(-sf));
                float gg = tanhf(sgg);
                float og = 1.f / (1.f + __expf(-so));
                float c_new = fg * c_st[p] + ig * gg;
                float h_new = og * tanhf(c_new);
                float hn = m[p] ? h_new : h_st[p];
                float cn = m[p] ? c_new : c_st[p];
                h_st[p] = hn; c_st[p] = cn;
                Hout[((size_t)t * BB + b) * 1024 + dir * HD + k] =
                    (unsigned short)f2bf(m[p] ? h_new : 0.f);
            }
        }

        // ---- publish h into buf[s+1] (ALL slots; 8B atomic stores; no barrier) ----
        {
            int i0 = (int)(unsigned short)f2bf(kok ? h_st[0] : 0.f);
            int i1 = (int)(unsigned short)f2bf(kok ? h_st[1] : 0.f);
            int a0 = __shfl_down(i0, 1), c0s = __shfl_down(i0, 2), d0 = __shfl_down(i0, 3);
            int a1 = __shfl_down(i1, 1), c1s = __shfl_down(i1, 2), d1 = __shfl_down(i1, 3);
            if ((lk & 3) == 0) {
                unsigned long long p0 = (unsigned long long)(unsigned)(i0 | (a0 << 16))
                                      | ((unsigned long long)(unsigned)(c0s | (d0 << 16)) << 32);
                unsigned long long p1 = (unsigned long long)(unsigned)(i1 | (a1 << 16))
                                      | ((unsigned long long)(unsigned)(c1s | (d1 << 16)) << 32);
                int idx0 = bsl * 512 + (b0v + 16 * (lk >> 3)) * 8 + (lk & 7);
                int idx1 = bsl * 512 + (b1v + 16 * (lk >> 3)) * 8 + (lk & 7);
                __hip_atomic_store((unsigned long long*)(bufw + idx0), p0,
                                   __ATOMIC_RELAXED, __HIP_MEMORY_SCOPE_AGENT);
                __hip_atomic_store((unsigned long long*)(bufw + idx1), p1,
                                   __ATOMIC_RELAXED, __HIP_MEMORY_SCOPE_AGENT);
            }
        }

        // ---- prefetch next step's G (raw) + mask: overlaps next poll-stage ----
        if (s + 1 < L) {
            int tn = dir ? (L - 2 - s) : (s + 1);
            if (kok) {
                const unsigned short* gr0 = Gd + ((size_t)tn * BB + b0v) * 2000 + k;
                const unsigned short* gr1 = Gd + ((size_t)tn * BB + b1v) * 2000 + k;
                gpraw[0][0] = gr0[0]; gpraw[0][1] = gr0[HD]; gpraw[0][2] = gr0[2 * HD]; gpraw[0][3] = gr0[3 * HD];
                gpraw[1][0] = gr1[0]; gpraw[1][1] = gr1[HD]; gpraw[1][2] = gr1[2 * HD]; gpraw[1][3] = gr1[3 * HD];
                m[0] = x[b0v * TT + tn] > 0;
                m[1] = x[b1v * TT + tn] > 0;
            }
        }
    }
}

// -------- output projection: Y (T,B,32) = bf16HS @ Wo^T + bo, masked ----------------
__global__ void outproj_kernel(const unsigned short* __restrict__ HS,
                               const float* __restrict__ Wo,
                               const float* __restrict__ bo, const int* __restrict__ x,
                               float* __restrict__ Y) {
    int idx = blockIdx.x * 256 + threadIdx.x;
    int r = idx >> 5;
    int n = idx & 31;
    int t = r >> 4;
    int b = r & 15;
    float out = 0.f;
    if (x[b * TT + t] > 0) {
        const unsigned short* h = HS + (size_t)r * 1024;
        const float* wrow = Wo + (size_t)n * 1000;
        float s = 0.f;
#pragma unroll 4
        for (int q = 0; q < 1000; q += 8) {
            short8 hv = *(const short8*)(h + q);
            float4 w0 = *(const float4*)(wrow + q);
            float4 w1 = *(const float4*)(wrow + q + 4);
            s += bf2f((unsigned short)hv[0]) * w0.x + bf2f((unsigned short)hv[1]) * w0.y
               + bf2f((unsigned short)hv[2]) * w0.z + bf2f((unsigned short)hv[3]) * w0.w
               + bf2f((unsigned short)hv[4]) * w1.x + bf2f((unsigned short)hv[5]) * w1.y
               + bf2f((unsigned short)hv[6]) * w1.z + bf2f((unsigned short)hv[7]) * w1.w;
        }
        out = s + bo[n];
    }
    Y[idx] = out;
}

// ---------------- CRF: gold score + forward scan ----------------
__global__ __launch_bounds__(1024) void crf_kernel(
    const float* __restrict__ Y, const int* __restrict__ x, const int* __restrict__ y0,
    const float* __restrict__ trans, float* __restrict__ out_pb) {
    int b = blockIdx.x;
    int tid = threadIdx.x;
    int i = tid >> 5;
    int j = tid & 31;
    float tr_ij = trans[i * 32 + j];

    __shared__ float sc[32];
    __shared__ float wred[16];
    __shared__ float goldS;

    float gp = 0.f;
    if (tid < TT) {
        int t = tid;
        int xm = x[b * TT + t];
        float mf = (xm > 0) ? 1.f : 0.f;
        int ynext = y0[b * TT + t];
        int yprev = (t == 0) ? 1 : y0[b * TT + t - 1];
        gp = Y[((size_t)t * BB + b) * 32 + ynext] + trans[ynext * 32 + yprev] * mf;
    }
#pragma unroll
    for (int d = 32; d >= 1; d >>= 1) gp += __shfl_down(gp, d);
    if ((tid & 63) == 0) wred[tid >> 6] = gp;
    __syncthreads();
    if (tid == 0) {
        float s = 0.f;
        for (int ww = 0; ww < 16; ++ww) s += wred[ww];
        goldS = s;
    }
    if (tid < 32) sc[tid] = (tid == 1) ? 0.f : NEG;
    __syncthreads();

    for (int t = 0; t < TT; ++t) {
        float sj = sc[j];
        float z = sj + tr_ij;
        float mx = z;
#pragma unroll
        for (int d = 16; d >= 1; d >>= 1) mx = fmaxf(mx, __shfl_xor(mx, d));
        float e = __expf(z - mx);
#pragma unroll
        for (int d = 16; d >= 1; d >>= 1) e += __shfl_xor(e, d);
        float cm = sj;
#pragma unroll
        for (int d = 16; d >= 1; d >>= 1) cm = fmaxf(cm, __shfl_xor(cm, d));
        float emit_i = Y[((size_t)t * BB + b) * 32 + i];
        float newv = emit_i + mx + __logf(e);
        int mm = x[b * TT + t] > 0;
        __syncthreads();
        if (j == 0) sc[i] = mm ? newv : cm;
        __syncthreads();
    }

    if (tid < 32) {
        float v = sc[tid];
        float mx = v;
#pragma unroll
        for (int d = 16; d >= 1; d >>= 1) mx = fmaxf(mx, __shfl_xor(mx, d));
        float e = __expf(v - mx);
#pragma unroll
        for (int d = 16; d >= 1; d >>= 1) e += __shfl_xor(e, d);
        if (tid == 0) out_pb[b] = (mx + __logf(e)) - goldS;
    }
}

__global__ void final_kernel(const float* __restrict__ out_pb, float* __restrict__ out) {
    if (threadIdx.x == 0 && blockIdx.x == 0) {
        float s = 0.f;
        for (int b = 0; b < BB; ++b) s += out_pb[b];
        out[0] = s / (float)BB;
    }
}

extern "C" void kernel_launch(void* const* d_in, const int* in_sizes, int n_in,
                              void* d_out, int out_size, void* d_ws, size_t ws_size,
                              hipStream_t stream) {
    const int*   x     = (const int*)d_in[0];
    const int*   y0    = (const int*)d_in[1];
    const float* EW    = (const float*)d_in[2];
    const float* Wih0  = (const float*)d_in[3];
    const float* Whh0  = (const float*)d_in[4];
    const float* bih0  = (const float*)d_in[5];
    const float* bhh0  = (const float*)d_in[6];
    const float* Wih1  = (const float*)d_in[7];
    const float* Whh1  = (const float*)d_in[8];
    const float* bih1  = (const float*)d_in[9];
    const float* bhh1  = (const float*)d_in[10];
    const float* Wo    = (const float*)d_in[11];
    const float* bo    = (const float*)d_in[12];
    const float* trans = (const float*)d_in[13];
    const float* h0    = (const float*)d_in[14];
    const float* c0    = (const float*)d_in[15];

    float* ws = (float*)d_ws;
    // Layout (float offsets), total 31,803,393 floats = 127.2 MB (< R3-proven 134 MB):
    //   [0, 524288)            XS bf16 (8192x128); Y fp32(262144)+crfbuf alias
    //   [524288, 16908288)     Gh: fp16 (2, 8192, 2000)
    //   [16908288, 21102592)   H0 bf16 (8192 x 1024)
    //   [21102592, 25296896)   HS bf16 (8192 x 1024)
    //   [25296896, 25552896)   Wb0 bf16 (2,2000,128)
    //   [25552896, 27600896)   Wb1 bf16 (2,2000,1024)
    //   [27600896, 31803392)   hseq: 2 dirs x 513 x 8192 bf16 (shared by both layers)
    //   [31803392]             mlen (1 int)
    unsigned short* XS = (unsigned short*)ws;
    float* Y      = ws;
    float* crfbuf = ws + 262144;
    unsigned short* Gh   = (unsigned short*)(ws + 524288);
    unsigned short* H0b  = (unsigned short*)(ws + 16908288);
    unsigned short* HSb  = (unsigned short*)(ws + 21102592);
    unsigned short* Wb0  = (unsigned short*)(ws + 25296896);
    unsigned short* Wb1  = (unsigned short*)(ws + 25552896);
    unsigned short* hseq = (unsigned short*)(ws + 27600896);
    int* mlen     = (int*)(ws + 31803392);
    const int nsent64 = 2 * (TT + 1) * 8192 / 4;   // 2,101,248 u64 words

    // Phase 0: maxlen + sentinel fill #1
    maxlen_kernel<<<1, 512, 0, stream>>>(x, mlen);
    sentfill_kernel<<<(nsent64 + 255) / 256, 256, 0, stream>>>((unsigned long long*)hseq, nsent64);

    // Phase 1: embedding -> bf16 XS (padded K=128); weight conversions
    embed_kernel<<<4096, 256, 0, stream>>>(x, EW, XS);
    wconv_kernel<<<(512000 + 255) / 256, 256, 0, stream>>>(Wih0, Wb0, 100, 128, 512000);
    wconv_kernel<<<(4096000 + 255) / 256, 256, 0, stream>>>(Wih1, Wb1, 1000, 1024, 4096000);

    // Phase 2: layer-0 input projections (MFMA, Kpad=128) -> fp16 Gh; zero H0 pads
    gemm_mfma<<<dim3(64, 32, 2), 256, 0, stream>>>(XS, Wb0, bih0, bhh0, Gh, 128);
    padzero_kernel<<<(98304 + 255) / 256, 256, 0, stream>>>((int*)H0b);

    // Phase 3: layer-0 recurrence -> bf16 H0 (data-is-flag, plain launch)
    rec10_kernel<<<32, 256, 0, stream>>>(Gh, Whh0, x, h0, c0, 0, H0b, hseq, mlen);

    // Phase 4: layer-1 input projections (MFMA, Kpad=1024) -> fp16 Gh; refill hseq
    gemm_mfma<<<dim3(64, 32, 2), 256, 0, stream>>>(H0b, Wb1, bih1, bhh1, Gh, 1024);
    sentfill_kernel<<<(nsent64 + 255) / 256, 256, 0, stream>>>((unsigned long long*)hseq, nsent64);

    // Phase 5: layer-1 recurrence -> bf16 HS
    rec10_kernel<<<32, 256, 0, stream>>>(Gh, Whh1, x, h0, c0, 2, HSb, hseq, mlen);

    // Phase 6: output projection (masked; bf16 HS, stride 1024)
    outproj_kernel<<<1024, 256, 0, stream>>>(HSb, Wo, bo, x, Y);

    // Phase 7: CRF gold + forward scan
    crf_kernel<<<BB, 1024, 0, stream>>>(Y, x, y0, trans, crfbuf);

    // Phase 8: mean
    final_kernel<<<1, 64, 0, stream>>>(crfbuf, (float*)d_out);
}